// Round 6
// baseline (198.224 us; speedup 1.0000x reference)
//
#include <hip/hip_runtime.h>
#include <hip/hip_cooperative_groups.h>
#include <cstdint>

namespace cg = cooperative_groups;

#define B_ 2
#define E_ 16
#define HW_ 46080
#define P_ 92160
#define N_ 12
#define NINST 24
#define NBINS 512          // err in [0,2] -> bin = min(511, err*256)
#define BINSCALE 256.0f
#define CHUNKS 90          // 1024-px chunks per batch
#define GRID (B_*CHUNKS)   // 180 blocks

typedef unsigned long long u64;
typedef unsigned int u32;

// ws float layout (first 8 KB, zeroed by host memset):
//   sumEmb[24][16] @0, sumSq[24][16] @384, cnt[24] @768, vA[24][16] @1024,
//   vB[24][16] @1408, vK[24] @1792
// hist u64[24][512] @ +8 KB (96 KB, zeroed by host memset)
__global__ __launch_bounds__(256) void k_fused(const float* __restrict__ mf1,
                                               const float* __restrict__ mf2,
                                               const int* __restrict__ gt,
                                               float* __restrict__ wsf,
                                               u64* __restrict__ hist,
                                               float* __restrict__ out){
  cg::grid_group gg = cg::this_grid();
  __shared__ u32 smem[N_*NBINS];          // 24 KB: phase1 red[12][33] / phase3 hist
  __shared__ float cA[N_*E_], cB[N_*E_], cK[N_];
  __shared__ u64 bw[4], bb[4];
  __shared__ float rs[4];

  float* sumEmb = wsf;
  float* sumSq  = wsf + 384;
  float* cnt    = wsf + 768;
  float* vA     = wsf + 1024;
  float* vB     = wsf + 1408;
  float* vK     = wsf + 1792;

  const int tid  = threadIdx.x;
  const int lane = tid & 63;
  const int bid  = blockIdx.x;           // 0..179
  const int b    = bid / CHUNKS;
  const int chunk= bid - b*CHUNKS;
  const int pbase= chunk*1024;           // never straddles HW_ (45*1024 = HW_)
  const int t    = (pbase >= HW_);
  const int r0   = pbase - t*HW_ + tid*4;
  const float* ep = (t ? mf2 : mf1) + (size_t)b*E_*HW_;

  // ---------------- phase 1: masked sum/sumsq/count ----------------
  float* red = (float*)smem;             // [12][33]
  for(int i=tid; i<N_*33; i+=256) red[i] = 0.f;

  float4 x[E_];                          // emb chunk: read ONCE, reused in phase 3
  #pragma unroll
  for(int e=0;e<E_;e++) x[e] = *(const float4*)&ep[(size_t)e*HW_ + r0];
  __syncthreads();

  #pragma unroll
  for(int n=0;n<N_;n++){
    int bn = b*N_ + n;
    int4 g4 = *(const int4*)&gt[(size_t)bn*P_ + pbase + tid*4];
    float m0=(float)g4.x, m1=(float)g4.y, m2=(float)g4.z, m3=(float)g4.w;
    float vals[33];
    vals[32] = m0+m1+m2+m3;
    #pragma unroll
    for(int e=0;e<E_;e++){
      float4 xe = x[e];
      float a0=m0*xe.x, a1=m1*xe.y, a2=m2*xe.z, a3=m3*xe.w;
      vals[e] = (a0+a1)+(a2+a3);
      float qq = a0*xe.x; qq=fmaf(a1,xe.y,qq); qq=fmaf(a2,xe.z,qq); qq=fmaf(a3,xe.w,qq);
      vals[E_+e] = qq;
    }
    float mine = 0.f;
    #pragma unroll
    for(int v=0; v<33; v++){
      float tt = vals[v];
      #pragma unroll
      for(int o=1;o<64;o<<=1) tt += __shfl_xor(tt, o, 64);
      if(lane==v) mine = tt;
    }
    if(lane<33) atomicAdd(&red[n*33+lane], mine);
  }
  __syncthreads();
  for(int i=tid; i<N_*33; i+=256){
    int n = i/33, j = i - n*33;
    int bn = b*N_ + n;
    float v = red[i];
    if(j<16)       atomicAdd(&sumEmb[bn*16+j], v);
    else if(j<32)  atomicAdd(&sumSq [bn*16+j-16], v);
    else           atomicAdd(&cnt[bn], v);
  }
  gg.sync();

  // ---------------- fin: blocks 0..23 compute vA/vB/vK ----------------
  if(bid < NINST){
    int bn = bid;
    if(tid < E_){
      float c  = cnt[bn];
      float mu = sumEmb[bn*16+tid] / c;
      float v  = (sumSq[bn*16+tid] - c*mu*mu) / (c - 1.f);
      vA[bn*16+tid] = v;
      vB[bn*16+tid] = -2.f*mu*v;
      cA[tid] = mu*mu*v;                 // scratch
    }
    __syncthreads();
    if(tid==0){
      float k=0.f;
      #pragma unroll
      for(int e=0;e<E_;e++) k += cA[e];
      vK[bn] = k;
    }
  }
  gg.sync();

  // ---------------- phase 3: err histogram (emb reused from regs) ----------
  for(int i=tid; i<N_*NBINS; i+=256) smem[i] = 0u;
  for(int i=tid; i<N_*E_; i+=256){ cA[i]=vA[b*N_*E_+i]; cB[i]=vB[b*N_*E_+i]; }
  if(tid<N_) cK[tid]=vK[b*N_+tid];
  __syncthreads();

  #pragma unroll
  for(int n=0;n<N_;n++){
    int bn = b*N_ + n;
    float a[E_], bb2[E_];
    #pragma unroll
    for(int e=0;e<E_;e++){ a[e]=cA[n*E_+e]; bb2[e]=cB[n*E_+e]; }
    float kk = cK[n];
    int4 g4 = *(const int4*)&gt[(size_t)bn*P_ + pbase + tid*4];
    int mi[4] = {g4.x, g4.y, g4.z, g4.w};
    #pragma unroll
    for(int k=0;k<4;k++){
      float d = kk;
      #pragma unroll
      for(int e=0;e<E_;e++){
        float xv = (k==0)?x[e].x : (k==1)?x[e].y : (k==2)?x[e].z : x[e].w;
        d = fmaf(xv, fmaf(xv, a[e], bb2[e]), d);   // vA*x^2 + vB*x
      }
      float logits = 2.f*__expf(-0.5f*d) - 1.f;
      float ev = fmaxf(1.f - logits*(2.f*(float)mi[k] - 1.f), 0.f);  // [0,2]
      int bin = min(NBINS-1, (int)(ev * BINSCALE));
      atomicAdd(&smem[n*NBINS + bin], 0x10000u | (u32)mi[k]);
    }
  }
  __syncthreads();
  for(int i=tid; i<N_*NBINS; i+=256){
    u32 v = smem[i];
    if(v){
      int n = i >> 9, bin = i & (NBINS-1);
      atomicAdd(&hist[(size_t)(b*N_+n)*NBINS + bin],
                ((u64)(v>>16)<<32) | (u64)(v & 0xffffu));
    }
  }
  gg.sync();

  // ---------------- bins: blocks 0..23, descending scan + telescoped dot ----
  if(bid < NINST){
    int bn = bid;
    const u64* h = hist + (size_t)bn*NBINS;
    const int PT = NBINS/256;   // 2
    int wave = tid >> 6;

    u64 loc[PT]; u64 s = 0;
    #pragma unroll
    for(int k=0;k<PT;k++){ loc[k] = h[NBINS-1 - (tid*PT + k)]; s += loc[k]; }
    u64 sc = s;
    #pragma unroll
    for(int off=1;off<64;off<<=1){ u64 v = __shfl_up(sc, off, 64); if(lane>=off) sc += v; }
    if(lane==63) bw[wave] = sc;
    __syncthreads();
    if(tid==0){
      u64 run = 0;
      #pragma unroll
      for(int w=0;w<4;w++){ bb[w] = run; run += bw[w]; }
    }
    __syncthreads();
    u64 excl = bb[wave] + (sc - s);

    float G = cnt[bn];
    float lsum = 0.f;
    #pragma unroll
    for(int k=0;k<PT;k++){
      u64 lv = loc[k];
      u32 cb = (u32)(lv>>32), lb = (u32)(lv & 0xffffffffu);
      if(cb){
        int bin = NBINS-1 - (tid*PT + k);
        float mid = ((float)bin + 0.5f) * (1.0f/BINSCALE);
        float i0 = (float)(u32)(excl>>32);
        float c0 = (float)(u32)(excl & 0xffffffffu);
        float c1 = c0 + (float)lb;
        float jend   = 1.f - (G - c1)/(G + i0 + (float)cb - c1);
        float jstart = 1.f - (G - c0)/(G + i0 - c0);
        lsum += mid * (jend - jstart);
      }
      excl += lv;
    }
    float tot = 0.f;
    {
      float v = lsum;
      #pragma unroll
      for(int o=32;o>0;o>>=1) v += __shfl_down(v, o, 64);
      tot = v;
    }
    if(lane==0) rs[wave] = tot;
    __syncthreads();
    if(tid==0) atomicAdd(out, (rs[0]+rs[1]+rs[2]+rs[3]) * (1.0f/(float)NINST));
  }
}

extern "C" void kernel_launch(void* const* d_in, const int* in_sizes, int n_in,
                              void* d_out, int out_size, void* d_ws, size_t ws_size,
                              hipStream_t stream){
  const float* mf1 = (const float*)d_in[0];
  const float* mf2 = (const float*)d_in[1];
  const int*   gt  = (const int*)d_in[2];
  float* out = (float*)d_out;

  float* wsf  = (float*)d_ws;
  u64*   hist = (u64*)((char*)d_ws + 8192);
  size_t zbytes = 8192 + (size_t)NINST*NBINS*sizeof(u64);   // 8 KB + 96 KB

  hipMemsetAsync(d_ws, 0, zbytes, stream);
  hipMemsetAsync(d_out, 0, sizeof(float), stream);

  void* args[] = { (void*)&mf1, (void*)&mf2, (void*)&gt,
                   (void*)&wsf, (void*)&hist, (void*)&out };
  hipLaunchCooperativeKernel((const void*)k_fused, dim3(GRID), dim3(256),
                             args, 0, stream);
}